// Round 1
// baseline (1184.428 us; speedup 1.0000x reference)
//
#include <hip/hip_runtime.h>

typedef unsigned short u16;
typedef short s16x8 __attribute__((ext_vector_type(8)));
typedef float f32x4 __attribute__((ext_vector_type(4)));

#define NTOK 2048
#define DDIM 2048
#define HDIM 1408
#define CAP  2048
#define SLOT ((size_t)DDIM * (size_t)HDIM)   // elements per expert weight slot

// ---- workspace layout (bytes). total ~382 MiB ----
#define OFF_XB   ((size_t)0)                          // NTOK*DDIM bf16      = 8,388,608
#define OFF_W1T  ((size_t)8388608)                    // 17*SLOT bf16 [H,D] rows
#define OFF_W3T  (OFF_W1T + (size_t)17*SLOT*2)
#define OFF_W2T  (OFF_W3T + (size_t)17*SLOT*2)        // 17*SLOT bf16 [D,H] rows
#define OFF_H3   (OFF_W2T + (size_t)17*SLOT*2)        // 17*CAP*HDIM bf16
#define OFF_TOK  (OFF_H3 + (size_t)17*CAP*HDIM*2)     // 17*CAP int
#define OFF_WT   (OFF_TOK + (size_t)17*CAP*4)         // 17*CAP float
#define OFF_CNT  (OFF_WT + (size_t)17*CAP*4)          // 16 int (+pad)

__device__ __forceinline__ u16 f2bf(float f) {         // RNE fp32->bf16
  unsigned u = __float_as_uint(f);
  u += 0x7fffu + ((u >> 16) & 1u);
  return (u16)(u >> 16);
}

__device__ __forceinline__ int imin(int a, int b) { return a < b ? a : b; }

// async global->LDS, 16B per lane; LDS dest = wave-uniform base + lane*16
__device__ __forceinline__ void async_cp16(const void* g, void* l) {
  __builtin_amdgcn_global_load_lds(
      (const __attribute__((address_space(1))) unsigned int*)g,
      (__attribute__((address_space(3))) unsigned int*)l, 16, 0, 0);
}

// ---------------- x -> bf16 ----------------
__global__ __launch_bounds__(256) void cvt_x(const float* __restrict__ src,
                                             u16* __restrict__ dst, int n4) {
  int i = blockIdx.x * 256 + threadIdx.x;
  if (i >= n4) return;
  float4 v = ((const float4*)src)[i];
  ushort4 o;
  o.x = f2bf(v.x); o.y = f2bf(v.y); o.z = f2bf(v.z); o.w = f2bf(v.w);
  ((ushort4*)dst)[i] = o;
}

// ---------------- transpose + convert: src [R,C] f32 -> dst [C,R] bf16 ----------------
__global__ __launch_bounds__(256) void transpose_cvt(const float* __restrict__ src,
                                                     u16* __restrict__ dst,
                                                     int R, int C) {
  __shared__ float tile[64][65];
  size_t slice = (size_t)blockIdx.z * (size_t)R * (size_t)C;
  src += slice; dst += slice;
  int r0 = blockIdx.y * 64, c0 = blockIdx.x * 64;
  int tid = threadIdx.x;
  for (int s = tid; s < 1024; s += 256) {           // 64x64 = 1024 float4 slots
    int row = s >> 4;
    int c4 = (s & 15) << 2;
    float4 v = *(const float4*)(src + (size_t)(r0 + row) * C + c0 + c4);
    tile[row][c4] = v.x; tile[row][c4 + 1] = v.y;
    tile[row][c4 + 2] = v.z; tile[row][c4 + 3] = v.w;
  }
  __syncthreads();
  for (int s = tid; s < 1024; s += 256) {
    int crow = s >> 4;
    int r4 = (s & 15) << 2;
    ushort4 o;
    o.x = f2bf(tile[r4 + 0][crow]);
    o.y = f2bf(tile[r4 + 1][crow]);
    o.z = f2bf(tile[r4 + 2][crow]);
    o.w = f2bf(tile[r4 + 3][crow]);
    *(ushort4*)(dst + (size_t)(c0 + crow) * R + r0 + r4) = o;
  }
}

// ---------------- gate: logits, sigmoid+bias, top-4, renorm, build expert lists ----------------
__global__ __launch_bounds__(256) void gate_kernel(const float* __restrict__ x,
                                                   const float* __restrict__ gw,
                                                   const float* __restrict__ gb,
                                                   int* __restrict__ tok,
                                                   float* __restrict__ wt,
                                                   int* __restrict__ counts) {
  int t = blockIdx.x;
  __shared__ float lsX[DDIM];
  __shared__ float lsLogit[16];
  int tid = threadIdx.x;
  const float4* xr = (const float4*)(x + (size_t)t * DDIM);
  for (int s = tid; s < DDIM / 4; s += 256) {
    float4 v = xr[s];
    lsX[s * 4 + 0] = v.x; lsX[s * 4 + 1] = v.y;
    lsX[s * 4 + 2] = v.z; lsX[s * 4 + 3] = v.w;
  }
  if (tid == 17) { tok[16 * CAP + t] = t; wt[16 * CAP + t] = 1.0f; }  // shared-expert list
  __syncthreads();
  int e = tid >> 4, sub = tid & 15;
  const float* gwe = gw + (size_t)e * DDIM;
  float p = 0.f;
  for (int d = sub; d < DDIM; d += 16) p += lsX[d] * gwe[d];
  p += __shfl_xor(p, 8, 16);
  p += __shfl_xor(p, 4, 16);
  p += __shfl_xor(p, 2, 16);
  p += __shfl_xor(p, 1, 16);
  if (sub == 0) lsLogit[e] = p;
  __syncthreads();
  if (tid == 0) {
    float s[16];
    for (int i = 0; i < 16; i++) s[i] = 1.f / (1.f + expf(-lsLogit[i])) + gb[i];
    unsigned used = 0;
    int sel[4]; float sw[4]; float sum = 0.f;
    for (int k = 0; k < 4; k++) {
      int bi = -1; float bv = -1e30f;
      for (int i = 0; i < 16; i++)
        if (!((used >> i) & 1u) && s[i] > bv) { bv = s[i]; bi = i; }
      used |= 1u << bi; sel[k] = bi; sw[k] = bv; sum += bv;
    }
    float inv = 1.f / sum;
    for (int k = 0; k < 4; k++) {
      int pos = atomicAdd(&counts[sel[k]], 1);
      tok[sel[k] * CAP + pos] = t;
      wt[sel[k] * CAP + pos] = sw[k] * inv;
    }
  }
}

// ---------------- GEMM1: h3 = act( gather(x) @ W1 , gather(x) @ W3 ) ----------------
// A: gathered xb rows [128, 32] bf16; B: W1t/W3t rows (n over H) [128, 32]; K over D.
__global__ __launch_bounds__(256) void gemm1(const u16* __restrict__ xb,
                                             const u16* __restrict__ w1t,
                                             const u16* __restrict__ w3t,
                                             const int* __restrict__ tok,
                                             const int* __restrict__ counts,
                                             u16* __restrict__ h3) {
  int e = blockIdx.z;
  int cnt = (e == 16) ? NTOK : counts[e];
  int m0 = blockIdx.y * 128;
  if (m0 >= cnt) return;
  int n0 = blockIdx.x * 128;
  const u16* B1 = w1t + (size_t)e * SLOT;   // [HDIM rows][DDIM] bf16
  const u16* B3 = w3t + (size_t)e * SLOT;

  __shared__ alignas(16) u16 lsA[128 * 32];
  __shared__ alignas(16) u16 lsB1[128 * 32];
  __shared__ alignas(16) u16 lsB3[128 * 32];

  int tid = threadIdx.x, w = tid >> 6, lane = tid & 63;
  int lrow = lane >> 2;
  int lcolb = (lane & 3) * 16;                  // byte offset within 64B row
  int ra0 = w * 32 + lrow, ra1 = w * 32 + 16 + lrow;
  int t0 = tok[e * CAP + imin(m0 + ra0, cnt - 1)];
  int t1 = tok[e * CAP + imin(m0 + ra1, cnt - 1)];
  const char* gA0 = (const char*)(xb + (size_t)t0 * DDIM) + lcolb;
  const char* gA1 = (const char*)(xb + (size_t)t1 * DDIM) + lcolb;
  const char* gB1a = (const char*)(B1 + (size_t)(n0 + ra0) * DDIM) + lcolb;
  const char* gB1b = (const char*)(B1 + (size_t)(n0 + ra1) * DDIM) + lcolb;
  const char* gB3a = (const char*)(B3 + (size_t)(n0 + ra0) * DDIM) + lcolb;
  const char* gB3b = (const char*)(B3 + (size_t)(n0 + ra1) * DDIM) + lcolb;
  u16* dA0 = lsA + (w * 32) * 32;      u16* dA1 = lsA + (w * 32 + 16) * 32;
  u16* dB1a = lsB1 + (w * 32) * 32;    u16* dB1b = lsB1 + (w * 32 + 16) * 32;
  u16* dB3a = lsB3 + (w * 32) * 32;    u16* dB3b = lsB3 + (w * 32 + 16) * 32;

  f32x4 acc1[4][4] = {}; f32x4 acc3[4][4] = {};
  int lr = lane & 15, quad = lane >> 4;
  int wm = (w >> 1) * 64, wn = (w & 1) * 64;

  for (int kk = 0; kk < DDIM / 32; ++kk) {
    async_cp16(gA0, dA0);  async_cp16(gA1, dA1);
    async_cp16(gB1a, dB1a); async_cp16(gB1b, dB1b);
    async_cp16(gB3a, dB3a); async_cp16(gB3b, dB3b);
    gA0 += 64; gA1 += 64; gB1a += 64; gB1b += 64; gB3a += 64; gB3b += 64;
    __syncthreads();                     // drains vmcnt -> LDS data visible
    s16x8 af[4], b1f[4], b3f[4];
#pragma unroll
    for (int i = 0; i < 4; ++i)
      af[i] = *(const s16x8*)(lsA + (wm + i * 16 + lr) * 32 + quad * 8);
#pragma unroll
    for (int j = 0; j < 4; ++j) {
      b1f[j] = *(const s16x8*)(lsB1 + (wn + j * 16 + lr) * 32 + quad * 8);
      b3f[j] = *(const s16x8*)(lsB3 + (wn + j * 16 + lr) * 32 + quad * 8);
    }
#pragma unroll
    for (int i = 0; i < 4; ++i)
#pragma unroll
      for (int j = 0; j < 4; ++j) {
        acc1[i][j] = __builtin_amdgcn_mfma_f32_16x16x32_bf16(af[i], b1f[j], acc1[i][j], 0, 0, 0);
        acc3[i][j] = __builtin_amdgcn_mfma_f32_16x16x32_bf16(af[i], b3f[j], acc3[i][j], 0, 0, 0);
      }
    __syncthreads();
  }

  bool routed = (e < 16);
  size_t hbase = (size_t)e * CAP;
#pragma unroll
  for (int i = 0; i < 4; ++i) {
#pragma unroll
    for (int r = 0; r < 4; ++r) {
      int rl = wm + i * 16 + quad * 4 + r;
      int grow = m0 + rl;
      if (grow >= cnt) continue;
      u16* orow = h3 + (hbase + grow) * HDIM + n0 + wn + lr;
#pragma unroll
      for (int j = 0; j < 4; ++j) {
        float c1 = acc1[i][j][r], c3 = acc3[i][j][r];
        float hv;
        if (routed) { float z = c1 * c3; hv = z / (1.f + __expf(-z)); }  // silu(h1*h2)
        else        { hv = c1 / (1.f + __expf(-c1)) * c3; }              // silu(h1)*h2
        orow[j * 16] = f2bf(hv);
      }
    }
  }
}

// ---------------- GEMM2: out += wt * (h3 @ W2) scattered by token ----------------
__global__ __launch_bounds__(256) void gemm2(const u16* __restrict__ h3,
                                             const u16* __restrict__ w2t,
                                             const int* __restrict__ tok,
                                             const float* __restrict__ wt,
                                             const int* __restrict__ counts,
                                             float* __restrict__ out) {
  int e = blockIdx.z;
  int cnt = (e == 16) ? NTOK : counts[e];
  int m0 = blockIdx.y * 128;
  if (m0 >= cnt) return;
  int n0 = blockIdx.x * 128;
  const u16* B = w2t + (size_t)e * SLOT;   // [DDIM rows][HDIM] bf16

  __shared__ alignas(16) u16 lsA[128 * 32];
  __shared__ alignas(16) u16 lsB[128 * 32];
  __shared__ int lsTok[128];
  __shared__ float lsWt[128];

  int tid = threadIdx.x, w = tid >> 6, lane = tid & 63;
  if (tid < 128) {
    int idx = imin(m0 + tid, cnt - 1);
    lsTok[tid] = tok[e * CAP + idx];
    lsWt[tid] = wt[e * CAP + idx];
  }
  int lrow = lane >> 2;
  int lcolb = (lane & 3) * 16;
  int ra0 = w * 32 + lrow, ra1 = w * 32 + 16 + lrow;
  size_t hbase = (size_t)e * CAP;
  const char* gA0 = (const char*)(h3 + (hbase + imin(m0 + ra0, cnt - 1)) * HDIM) + lcolb;
  const char* gA1 = (const char*)(h3 + (hbase + imin(m0 + ra1, cnt - 1)) * HDIM) + lcolb;
  const char* gB0 = (const char*)(B + (size_t)(n0 + ra0) * HDIM) + lcolb;
  const char* gB1 = (const char*)(B + (size_t)(n0 + ra1) * HDIM) + lcolb;
  u16* dA0 = lsA + (w * 32) * 32;  u16* dA1 = lsA + (w * 32 + 16) * 32;
  u16* dB0 = lsB + (w * 32) * 32;  u16* dB1 = lsB + (w * 32 + 16) * 32;

  f32x4 acc[4][4] = {};
  int lr = lane & 15, quad = lane >> 4;
  int wm = (w >> 1) * 64, wn = (w & 1) * 64;

  for (int kk = 0; kk < HDIM / 32; ++kk) {
    async_cp16(gA0, dA0); async_cp16(gA1, dA1);
    async_cp16(gB0, dB0); async_cp16(gB1, dB1);
    gA0 += 64; gA1 += 64; gB0 += 64; gB1 += 64;
    __syncthreads();
    s16x8 af[4], bf[4];
#pragma unroll
    for (int i = 0; i < 4; ++i)
      af[i] = *(const s16x8*)(lsA + (wm + i * 16 + lr) * 32 + quad * 8);
#pragma unroll
    for (int j = 0; j < 4; ++j)
      bf[j] = *(const s16x8*)(lsB + (wn + j * 16 + lr) * 32 + quad * 8);
#pragma unroll
    for (int i = 0; i < 4; ++i)
#pragma unroll
      for (int j = 0; j < 4; ++j)
        acc[i][j] = __builtin_amdgcn_mfma_f32_16x16x32_bf16(af[i], bf[j], acc[i][j], 0, 0, 0);
    __syncthreads();
  }

#pragma unroll
  for (int i = 0; i < 4; ++i) {
#pragma unroll
    for (int r = 0; r < 4; ++r) {
      int rl = wm + i * 16 + quad * 4 + r;
      int grow = m0 + rl;
      if (grow >= cnt) continue;
      float wgt = lsWt[rl];
      float* orow = out + (size_t)lsTok[rl] * DDIM + n0 + wn + lr;
#pragma unroll
      for (int j = 0; j < 4; ++j)
        atomicAdd(orow + j * 16, acc[i][j][r] * wgt);
    }
  }
}

extern "C" void kernel_launch(void* const* d_in, const int* in_sizes, int n_in,
                              void* d_out, int out_size, void* d_ws, size_t ws_size,
                              hipStream_t stream) {
  const float* x      = (const float*)d_in[0];
  const float* gate_w = (const float*)d_in[1];
  const float* gate_b = (const float*)d_in[2];
  const float* w1s    = (const float*)d_in[3];
  const float* w2s    = (const float*)d_in[4];
  const float* w3s    = (const float*)d_in[5];
  const float* w1r    = (const float*)d_in[6];
  const float* w2r    = (const float*)d_in[7];
  const float* w3r    = (const float*)d_in[8];
  float* out = (float*)d_out;
  char* ws = (char*)d_ws;

  u16*   xb   = (u16*)(ws + OFF_XB);
  u16*   w1t  = (u16*)(ws + OFF_W1T);
  u16*   w3t  = (u16*)(ws + OFF_W3T);
  u16*   w2t  = (u16*)(ws + OFF_W2T);
  u16*   h3   = (u16*)(ws + OFF_H3);
  int*   tokl = (int*)(ws + OFF_TOK);
  float* wtl  = (float*)(ws + OFF_WT);
  int*   cnts = (int*)(ws + OFF_CNT);

  hipMemsetAsync(out, 0, (size_t)NTOK * DDIM * sizeof(float), stream);
  hipMemsetAsync(cnts, 0, 64, stream);

  cvt_x<<<(NTOK * DDIM / 4 + 255) / 256, 256, 0, stream>>>(x, xb, NTOK * DDIM / 4);

  // routed weights into slots 0..15, shared into slot 16
  transpose_cvt<<<dim3(HDIM / 64, DDIM / 64, 16), 256, 0, stream>>>(w1r, w1t, DDIM, HDIM);
  transpose_cvt<<<dim3(HDIM / 64, DDIM / 64, 16), 256, 0, stream>>>(w3r, w3t, DDIM, HDIM);
  transpose_cvt<<<dim3(DDIM / 64, HDIM / 64, 16), 256, 0, stream>>>(w2r, w2t, HDIM, DDIM);
  transpose_cvt<<<dim3(HDIM / 64, DDIM / 64, 1), 256, 0, stream>>>(w1s, w1t + 16 * SLOT, DDIM, HDIM);
  transpose_cvt<<<dim3(HDIM / 64, DDIM / 64, 1), 256, 0, stream>>>(w3s, w3t + 16 * SLOT, DDIM, HDIM);
  transpose_cvt<<<dim3(DDIM / 64, HDIM / 64, 1), 256, 0, stream>>>(w2s, w2t + 16 * SLOT, HDIM, DDIM);

  gate_kernel<<<NTOK, 256, 0, stream>>>(x, gate_w, gate_b, tokl, wtl, cnts);

  gemm1<<<dim3(HDIM / 128, NTOK / 128, 17), 256, 0, stream>>>(xb, w1t, w3t, tokl, cnts, h3);
  gemm2<<<dim3(DDIM / 128, NTOK / 128, 17), 256, 0, stream>>>(h3, w2t, tokl, wtl, cnts, out);
}